// Round 14
// baseline (7841.838 us; speedup 1.0000x reference)
//
#include <hip/hip_runtime.h>
#include <hip/hip_fp16.h>

// GRU 2-layer, B=256 S=1024 F=75 H=256.
// Round 14: R11 base + top-of-phase validation for BOTH tensors.
//  h0[p-1] gathered at C(p-1) right after publish (age ~60% phase), h1[p-2]
//  gathered at C(p-1) (age ~130%) -> both validated once at phase top, halves
//  concurrent. All 8 MFMA tiles then run in ONE section (no S2/S3 split):
//  3 barriers + 1 stall per phase (R11: 4 + 2). Carried gathers = 4 u32x4
//  per thread (own half only) to keep VGPR pressure low (R13 crash lesson).
//  Exchange protocol unchanged (tags, parity dbuf, equality, memset, latch).

#define NS 1024
#define NF 75
#define NH 256

#define W0S 360   // halves: 96(x pad) + 256(h) + 8 pad
#define W1S 520   // 256(h0) + 256(h1) + 8 pad
#define HCS 520   // hcat row halves: [h0 0..255 | h1 256..511] + pad
#define XSS 104   // 96 + 8 pad

#define W0_HALVES (48 * W0S)                 // 17280
#define W1_HALVES (48 * W1S)                 // 24960
#define IMG_HALVES (W0_HALVES + W1_HALVES)   // 42240 halves = 84480 B

// shared aliasing offsets (bytes)
#define HCAT_OFF 0
#define XS_OFF   16640
#define CT_OFF   23296
#define RED_OFF  31488

// d_ws layout (bytes)
#define WIMG_OFF 0
#define WIMG_BYTES (16 * IMG_HALVES * 2)
#define HX0_OFF WIMG_BYTES
#define HX_WORDS (2 * 16 * 16 * 256)
#define HX1_OFF (HX0_OFF + HX_WORDS * 4)
#define HX_TOTAL_BYTES (2 * HX_WORDS * 4)    // 1 MiB

typedef _Float16 f16x8 __attribute__((ext_vector_type(8)));
typedef float f32x4 __attribute__((ext_vector_type(4)));
typedef unsigned int u32x4 __attribute__((ext_vector_type(4)));

#define PINV(x) asm volatile("" : "+v"(x))

__device__ __forceinline__ void bar_lds() {
  asm volatile("s_waitcnt lgkmcnt(0)" ::: "memory");
  __builtin_amdgcn_s_barrier();
  __builtin_amdgcn_sched_barrier(0);
}

// MALL-routed coherent ops (sc0 sc1), placement-independent (R4..R11-proven)
__device__ __forceinline__ void st_u32_sys(unsigned* p, unsigned v) {
  asm volatile("global_store_dword %0, %1, off sc0 sc1" :: "v"(p), "v"(v) : "memory");
}
__device__ __forceinline__ void issue4_sys(const unsigned* p, u32x4& a, u32x4& b,
                                           u32x4& c, u32x4& d) {
  asm volatile(
      "global_load_dwordx4 %0, %4, off sc0 sc1\n\t"
      "global_load_dwordx4 %1, %4, off offset:16 sc0 sc1\n\t"
      "global_load_dwordx4 %2, %4, off offset:32 sc0 sc1\n\t"
      "global_load_dwordx4 %3, %4, off offset:48 sc0 sc1"
      : "=&v"(a), "=&v"(b), "=&v"(c), "=&v"(d) : "v"(p) : "memory");
}
__device__ __forceinline__ void ld4b_sys(const unsigned* p, u32x4& a, u32x4& b,
                                         u32x4& c, u32x4& d) {
  asm volatile(
      "global_load_dwordx4 %0, %4, off sc0 sc1\n\t"
      "global_load_dwordx4 %1, %4, off offset:16 sc0 sc1\n\t"
      "global_load_dwordx4 %2, %4, off offset:32 sc0 sc1\n\t"
      "global_load_dwordx4 %3, %4, off offset:48 sc0 sc1\n\t"
      "s_waitcnt vmcnt(0)"
      : "=&v"(a), "=&v"(b), "=&v"(c), "=&v"(d) : "v"(p) : "memory");
}

__device__ __forceinline__ bool tags_ok(const u32x4& a, const u32x4& b,
                                        const u32x4& c, const u32x4& e, unsigned tg) {
  u32x4 m4 = __builtin_elementwise_min(__builtin_elementwise_min(a, b),
                                       __builtin_elementwise_min(c, e));
  unsigned m = m4.x;
  m = m4.y < m ? m4.y : m;
  m = m4.z < m ? m4.z : m;
  m = m4.w < m ? m4.w : m;
  return (m >> 16) == tg;
}

__device__ __forceinline__ void unpack16(_Float16* d, const u32x4& a, const u32x4& b,
                                         const u32x4& c, const u32x4& e) {
  u32x4 w0 = { (a.x & 0xffffu) | (a.y << 16), (a.z & 0xffffu) | (a.w << 16),
               (b.x & 0xffffu) | (b.y << 16), (b.z & 0xffffu) | (b.w << 16) };
  u32x4 w1 = { (c.x & 0xffffu) | (c.y << 16), (c.z & 0xffffu) | (c.w << 16),
               (e.x & 0xffffu) | (e.y << 16), (e.z & 0xffffu) | (e.w << 16) };
  *(u32x4*)d = w0;
  *(u32x4*)(d + 8) = w1;
}

// Weight image per block j (halves): W0 [48][W0S] (x cols 0..74, h cols 96..351),
// W1 [48][W1S] (h0 cols 0..255, h1 cols 256..511); row = gate*16+u.
__global__ void prep_wimg(const float* __restrict__ wih0, const float* __restrict__ whh0,
                          const float* __restrict__ wih1, const float* __restrict__ whh1,
                          _Float16* __restrict__ wimg) {
  const int total = 16 * IMG_HALVES;
  for (int i = blockIdx.x * blockDim.x + threadIdx.x; i < total;
       i += gridDim.x * blockDim.x) {
    const int j = i / IMG_HALVES;
    int rem = i - j * IMG_HALVES;
    float val = 0.f;
    if (rem < W0_HALVES) {
      const int row = rem / W0S, k = rem - row * W0S;
      const int gate = row >> 4, u = row & 15;
      const int grow = gate * NH + j * 16 + u;
      if (k < NF) val = wih0[grow * NF + k];
      else if (k >= 96 && k < 352) val = whh0[grow * NH + (k - 96)];
    } else {
      rem -= W0_HALVES;
      const int row = rem / W1S, k = rem - row * W1S;
      const int gate = row >> 4, u = row & 15;
      const int grow = gate * NH + j * 16 + u;
      if (k < 256) val = wih1[grow * NH + k];
      else if (k < 512) val = whh1[grow * NH + (k - 256)];
    }
    wimg[i] = (_Float16)val;
  }
}

__global__ __launch_bounds__(512, 1) void gru_mfma(
    const float* __restrict__ x,
    const float* __restrict__ b_ih0, const float* __restrict__ b_hh0,
    const float* __restrict__ b_ih1, const float* __restrict__ b_hh1,
    const float* __restrict__ w_lin, const float* __restrict__ b_lin,
    const _Float16* __restrict__ wimg,
    unsigned* __restrict__ hx0, unsigned* __restrict__ hx1,
    float* __restrict__ out)
{
  const int tid = threadIdx.x;
  const int bid = blockIdx.x;
  const int gr = (bid & 7) + ((bid >> 7) << 3);
  const int j  = (bid >> 3) & 15;

  __shared__ f16x8 smem8[IMG_HALVES / 8];
  _Float16* Wst  = (_Float16*)smem8;
  _Float16* hcat = (_Float16*)((char*)smem8 + HCAT_OFF);
  _Float16* xs   = (_Float16*)((char*)smem8 + XS_OFF);
  float (*ctile)[64][4] = (float(*)[64][4])((char*)smem8 + CT_OFF);
  float (*red)[17]      = (float(*)[17])((char*)smem8 + RED_OFF);

  int dead = 0, spins = 0;

  // ---- stage weight image ----
  {
    const float4* src = (const float4*)(wimg + (size_t)j * IMG_HALVES);
    float4* dst = (float4*)Wst;
    for (int i = tid; i < IMG_HALVES / 8; i += 512) dst[i] = src[i];
  }

  const int t8 = tid & 255;
  const int row = t8 >> 4, u = t8 & 15, gu = j * 16 + u;
  const int wid = tid >> 6, lane = tid & 63;
  const int lrow = lane & 15, lko = (lane >> 4) * 8;
  const int chunk = gr * 4096 + row * 256 + u * 16;
  const bool half0 = (tid < 256);

  float gbr, gbz, gbnx, gbnh;
  if (half0) {
    gbr  = b_ih0[gu] + b_hh0[gu];
    gbz  = b_ih0[NH + gu] + b_hh0[NH + gu];
    gbnx = b_ih0[2 * NH + gu];
    gbnh = b_hh0[2 * NH + gu];
  } else {
    gbr  = b_ih1[gu] + b_hh1[gu];
    gbz  = b_ih1[NH + gu] + b_hh1[NH + gu];
    gbnx = b_ih1[2 * NH + gu];
    gbnh = b_hh1[2 * NH + gu];
  }

  __syncthreads();   // Sa: weights staged

  // ---- hoist per-wave B-fragments (one tile per wave) ----
  _Float16* W0s = Wst;
  _Float16* W1s = Wst + W0_HALVES;
  f16x8 Bf[16];
  if (wid == 0) {            // ct0 = L0-r
    const _Float16* wb = W0s + lrow * W0S + lko;
    #pragma unroll
    for (int i = 0; i < 11; ++i) { Bf[i] = *(const f16x8*)(wb + i * 32); PINV(Bf[i]); }
  } else if (wid == 1) {     // ct1 = L0-z
    const _Float16* wb = W0s + (16 + lrow) * W0S + lko;
    #pragma unroll
    for (int i = 0; i < 11; ++i) { Bf[i] = *(const f16x8*)(wb + i * 32); PINV(Bf[i]); }
  } else if (wid == 2) {     // ct2 = L0-nx (x-part only)
    const _Float16* wb = W0s + (32 + lrow) * W0S + lko;
    #pragma unroll
    for (int i = 0; i < 3; ++i) { Bf[i] = *(const f16x8*)(wb + i * 32); PINV(Bf[i]); }
  } else if (wid == 3) {     // ct3 = L0-nh (h-part)
    const _Float16* wb = W0s + (32 + lrow) * W0S + lko;
    #pragma unroll
    for (int i = 0; i < 8; ++i) { Bf[i] = *(const f16x8*)(wb + (3 + i) * 32); PINV(Bf[i]); }
  } else if (wid == 4) {     // ct4 = L1-r (h0 cols 0..7, h1 cols 8..15)
    const _Float16* wn = W1s + lrow * W1S + lko;
    #pragma unroll
    for (int i = 0; i < 16; ++i) { Bf[i] = *(const f16x8*)(wn + i * 32); PINV(Bf[i]); }
  } else if (wid == 5) {     // ct5 = L1-z
    const _Float16* wn = W1s + (16 + lrow) * W1S + lko;
    #pragma unroll
    for (int i = 0; i < 16; ++i) { Bf[i] = *(const f16x8*)(wn + i * 32); PINV(Bf[i]); }
  } else if (wid == 6) {     // ct6 = L1-nx (h0 cols)
    const _Float16* wn = W1s + (32 + lrow) * W1S + lko;
    #pragma unroll
    for (int i = 0; i < 8; ++i) { Bf[i] = *(const f16x8*)(wn + i * 32); PINV(Bf[i]); }
  } else {                   // ct7 = L1-nh (h1 cols)
    const _Float16* wn = W1s + (32 + lrow) * W1S + lko;
    #pragma unroll
    for (int i = 0; i < 8; ++i) { Bf[i] = *(const f16x8*)(wn + (8 + i) * 32); PINV(Bf[i]); }
  }
  __syncthreads();   // Sb: hoist done, weight bytes may be clobbered

  for (int i = tid; i < 16 * HCS; i += 512) hcat[i] = (_Float16)0.f;
  for (int i = tid; i < 2 * 16 * XSS; i += 512) xs[i] = (_Float16)0.f;

  int xr_[3], xc_[3]; bool xv_[3];
  #pragma unroll
  for (int i = 0; i < 3; ++i) {
    const int idx = i * 512 + tid;
    xv_[i] = idx < 16 * NF;
    xr_[i] = xv_[i] ? idx / NF : 0;
    xc_[i] = xv_[i] ? idx % NF : 0;
  }
  const float* __restrict__ xbase = x + (size_t)(gr * 16) * NS * NF;
  #pragma unroll
  for (int i = 0; i < 3; ++i)
    if (xv_[i]) xs[xr_[i] * XSS + xc_[i]] =
        (_Float16)xbase[(size_t)xr_[i] * NS * NF + xc_[i]];

  float h0f = 0.f, h1f = 0.f;
  u32x4 K0, K1, K2, K3;                  // carried own-half gather (16 VGPRs)
  __syncthreads();   // Sc

  for (int p = 0; p <= NS; ++p) {
    const int par = p & 1;

    // ---- A1: single validate point (both halves concurrent) ----
    if (half0) {
      if (p >= 1) {                      // h0[p-1], slot (p-1)&1, tag p
        asm volatile("s_waitcnt vmcnt(0)"
                     : "+v"(K0), "+v"(K1), "+v"(K2), "+v"(K3) :: "memory");
        const unsigned* a0 = hx0 + ((p - 1) & 1) * 65536 + chunk;
        while (!tags_ok(K0, K1, K2, K3, (unsigned)p)) {
          if (++spins > 200000) { dead = 1; break; }
          __builtin_amdgcn_s_sleep(1);
          ld4b_sys(a0, K0, K1, K2, K3);
        }
        unpack16(hcat + row * HCS + u * 16, K0, K1, K2, K3);
      }
    } else {
      if (p >= 2) {                      // h1[p-2], slot (p-2)&1 = p&1, tag p-1
        asm volatile("s_waitcnt vmcnt(0)"
                     : "+v"(K0), "+v"(K1), "+v"(K2), "+v"(K3) :: "memory");
        const unsigned* a1 = hx1 + par * 65536 + chunk;
        while (!tags_ok(K0, K1, K2, K3, (unsigned)(p - 1))) {
          if (++spins > 200000) { dead = 1; break; }
          __builtin_amdgcn_s_sleep(1);
          ld4b_sys(a1, K0, K1, K2, K3);
        }
        unpack16(hcat + row * HCS + 256 + u * 16, K0, K1, K2, K3);
      }
    }
    // x prefetch AFTER validate (keeps vmcnt window clean at the stall)
    float xf[3];
    if (p + 1 < NS) {
      #pragma unroll
      for (int i = 0; i < 3; ++i)
        if (xv_[i]) xf[i] = xbase[((size_t)xr_[i] * NS + (p + 1)) * NF + xc_[i]];
    }
    bar_lds();   // Bar1: hcat(h0[p-1], h1[p-2]) ready

    // ---- B1: ALL 8 MFMA tiles in one section ----
    {
      const _Float16* __restrict__ xp = xs + par * (16 * XSS) + lrow * XSS + lko;
      const _Float16* __restrict__ hp = hcat + lrow * HCS + lko;
      if (wid <= 1) {
        f16x8 xa0 = *(const f16x8*)(xp);
        f16x8 xa1 = *(const f16x8*)(xp + 32);
        f16x8 xa2 = *(const f16x8*)(xp + 64);
        f16x8 hf[8];
        #pragma unroll
        for (int kb = 0; kb < 8; ++kb) hf[kb] = *(const f16x8*)(hp + kb * 32);
        f32x4 a = {0.f, 0.f, 0.f, 0.f};
        a = __builtin_amdgcn_mfma_f32_16x16x32_f16(xa0, Bf[0], a, 0, 0, 0);
        a = __builtin_amdgcn_mfma_f32_16x16x32_f16(xa1, Bf[1], a, 0, 0, 0);
        a = __builtin_amdgcn_mfma_f32_16x16x32_f16(xa2, Bf[2], a, 0, 0, 0);
        #pragma unroll
        for (int kb = 0; kb < 8; ++kb)
          a = __builtin_amdgcn_mfma_f32_16x16x32_f16(hf[kb], Bf[3 + kb], a, 0, 0, 0);
        *(f32x4*)&ctile[wid][lane][0] = a;
      } else if (wid == 2) {
        f16x8 xa0 = *(const f16x8*)(xp);
        f16x8 xa1 = *(const f16x8*)(xp + 32);
        f16x8 xa2 = *(const f16x8*)(xp + 64);
        f32x4 a = {0.f, 0.f, 0.f, 0.f};
        a = __builtin_amdgcn_mfma_f32_16x16x32_f16(xa0, Bf[0], a, 0, 0, 0);
        a = __builtin_amdgcn_mfma_f32_16x16x32_f16(xa1, Bf[1], a, 0, 0, 0);
        a = __builtin_amdgcn_mfma_f32_16x16x32_f16(xa2, Bf[2], a, 0, 0, 0);
        *(f32x4*)&ctile[2][lane][0] = a;
      } else if (wid == 3) {
        f16x8 hf[8];
        #pragma unroll
        for (int kb = 0; kb < 8; ++kb) hf[kb] = *(const f16x8*)(hp + kb * 32);
        f32x4 a = {0.f, 0.f, 0.f, 0.f};
        #pragma unroll
        for (int kb = 0; kb < 8; ++kb)
          a = __builtin_amdgcn_mfma_f32_16x16x32_f16(hf[kb], Bf[kb], a, 0, 0, 0);
        *(f32x4*)&ctile[3][lane][0] = a;
      } else if (wid == 4 || wid == 5) {
        f16x8 hf[8], h1r[8];
        #pragma unroll
        for (int kb = 0; kb < 8; ++kb) hf[kb] = *(const f16x8*)(hp + kb * 32);
        #pragma unroll
        for (int kb = 0; kb < 8; ++kb) h1r[kb] = *(const f16x8*)(hp + 256 + kb * 32);
        f32x4 a = {0.f, 0.f, 0.f, 0.f};
        #pragma unroll
        for (int kb = 0; kb < 8; ++kb)
          a = __builtin_amdgcn_mfma_f32_16x16x32_f16(hf[kb], Bf[kb], a, 0, 0, 0);
        #pragma unroll
        for (int kb = 0; kb < 8; ++kb)
          a = __builtin_amdgcn_mfma_f32_16x16x32_f16(h1r[kb], Bf[8 + kb], a, 0, 0, 0);
        *(f32x4*)&ctile[wid][lane][0] = a;
      } else if (wid == 6) {
        f16x8 hf[8];
        #pragma unroll
        for (int kb = 0; kb < 8; ++kb) hf[kb] = *(const f16x8*)(hp + kb * 32);
        f32x4 a = {0.f, 0.f, 0.f, 0.f};
        #pragma unroll
        for (int kb = 0; kb < 8; ++kb)
          a = __builtin_amdgcn_mfma_f32_16x16x32_f16(hf[kb], Bf[kb], a, 0, 0, 0);
        *(f32x4*)&ctile[6][lane][0] = a;
      } else {
        f16x8 h1r[8];
        #pragma unroll
        for (int kb = 0; kb < 8; ++kb) h1r[kb] = *(const f16x8*)(hp + 256 + kb * 32);
        f32x4 a = {0.f, 0.f, 0.f, 0.f};
        #pragma unroll
        for (int kb = 0; kb < 8; ++kb)
          a = __builtin_amdgcn_mfma_f32_16x16x32_f16(h1r[kb], Bf[kb], a, 0, 0, 0);
        *(f32x4*)&ctile[7][lane][0] = a;
      }
    }
    // stage x[p+1]
    if (p + 1 < NS) {
      #pragma unroll
      for (int i = 0; i < 3; ++i)
        if (xv_[i]) xs[((p + 1) & 1) * (16 * XSS) + xr_[i] * XSS + xc_[i]] =
            (_Float16)xf[i];
    }
    bar_lds();   // Bar2: ctile ready; all hcat/xs(par) reads done

    // ---- C: concurrent gates + publish + gather issue ----
    const int li = ((row >> 2) << 4) | u, rg = row & 3;
    if (half0) {
      if (p < NS) {
        const float ar = ctile[0][li][rg] + gbr;
        const float az = ctile[1][li][rg] + gbz;
        const float nx = ctile[2][li][rg] + gbnx;
        const float nh = ctile[3][li][rg] + gbnh;
        const float r = 1.f / (1.f + __expf(-ar));
        const float z = 1.f / (1.f + __expf(-az));
        const float n = tanhf(nx + r * nh);
        h0f = (1.f - z) * n + z * h0f;
        union { _Float16 h; unsigned short s; } c; c.h = (_Float16)h0f;
        st_u32_sys(hx0 + par * 65536 + gr * 4096 + row * 256 + gu,
                   (unsigned)c.s | ((unsigned)(p + 1) << 16));
        issue4_sys(hx0 + par * 65536 + chunk, K0, K1, K2, K3);
      }
    } else {
      if (p >= 1) {
        const float ar = ctile[4][li][rg] + gbr;
        const float az = ctile[5][li][rg] + gbz;
        const float nx = ctile[6][li][rg] + gbnx;
        const float nh = ctile[7][li][rg] + gbnh;
        const float r = 1.f / (1.f + __expf(-ar));
        const float z = 1.f / (1.f + __expf(-az));
        const float n = tanhf(nx + r * nh);
        h1f = (1.f - z) * n + z * h1f;
        union { _Float16 h; unsigned short s; } c; c.h = (_Float16)h1f;
        st_u32_sys(hx1 + ((p - 1) & 1) * 65536 + gr * 4096 + row * 256 + gu,
                   (unsigned)c.s | ((unsigned)p << 16));
        issue4_sys(hx1 + ((p - 1) & 1) * 65536 + chunk, K0, K1, K2, K3);
      }
    }
    bar_lds();   // Bar3: ctile reads done (safe to overwrite next phase)
  }

  // ---- tail: half1 blocking-gathers h1[NS-1] (slot (NS-1)&1, tag NS) ----
  if (!half0) {
    u32x4 C0, C1, C2, C3;
    const unsigned* src = hx1 + ((NS - 1) & 1) * 65536 + chunk;
    for (;;) {
      ld4b_sys(src, C0, C1, C2, C3);
      if (tags_ok(C0, C1, C2, C3, (unsigned)NS)) break;
      if (++spins > 200000) { dead = 1; break; }
      __builtin_amdgcn_s_sleep(1);
    }
    unpack16(hcat + row * HCS + 256 + u * 16, C0, C1, C2, C3);
  }
  __syncthreads();
  if (half0) {
    float part = 0.f;
    #pragma unroll
    for (int e = 0; e < 16; ++e)
      part += (float)hcat[row * HCS + 256 + u * 16 + e] * w_lin[u * 16 + e];
    red[row][u] = part;
  }
  __syncthreads();
  if (j == 0 && tid < 16) {
    float s = 0.f;
    #pragma unroll
    for (int e = 0; e < 16; ++e) s += red[tid][e];
    out[gr * 16 + tid] = s + b_lin[0];
  }
}

extern "C" void kernel_launch(void* const* d_in, const int* in_sizes, int n_in,
                              void* d_out, int out_size, void* d_ws, size_t ws_size,
                              hipStream_t stream) {
  (void)in_sizes; (void)n_in; (void)out_size; (void)ws_size;
  const float* x     = (const float*)d_in[0];
  const float* w_ih0 = (const float*)d_in[1];
  const float* w_hh0 = (const float*)d_in[2];
  const float* b_ih0 = (const float*)d_in[3];
  const float* b_hh0 = (const float*)d_in[4];
  const float* w_ih1 = (const float*)d_in[5];
  const float* w_hh1 = (const float*)d_in[6];
  const float* b_ih1 = (const float*)d_in[7];
  const float* b_hh1 = (const float*)d_in[8];
  const float* w_lin = (const float*)d_in[9];
  const float* b_lin = (const float*)d_in[10];

  char* ws = (char*)d_ws;
  _Float16* wimg = (_Float16*)(ws + WIMG_OFF);
  unsigned* hx0  = (unsigned*)(ws + HX0_OFF);
  unsigned* hx1  = (unsigned*)(ws + HX1_OFF);

  hipMemsetAsync(ws + HX0_OFF, 0, HX_TOTAL_BYTES, stream);
  prep_wimg<<<1024, 256, 0, stream>>>(w_ih0, w_hh0, w_ih1, w_hh1, wimg);
  gru_mfma<<<256, 512, 0, stream>>>(x, b_ih0, b_hh0, b_ih1, b_hh1,
                                    w_lin, b_lin, wimg, hx0, hx1,
                                    (float*)d_out);
}

// Round 15
// 2492.760 us; speedup vs baseline: 3.1458x; 3.1458x over previous
//
#include <hip/hip_runtime.h>
#include <hip/hip_fp16.h>

// GRU 2-layer, B=256 S=1024 F=75 H=256.
// Round 15: R11 (proven 2373us) with ONE change: sequential W0/W1 staging
//  through a single 48KB LDS buffer -> static LDS 84480B -> 49152B ->
//  3 blocks/CU (was 1), 6 waves/SIMD. Exchange protocol, issue/validate
//  points, barrier structure: R11 verbatim. W1 rows lose pad (512 halves).

#define NS 1024
#define NF 75
#define NH 256

#define W0S 360   // halves: 96(x pad) + 256(h) + 8 pad
#define W1S 512   // 256(h0) + 256(h1), no pad (hoist is one-time)
#define HCS 520   // hcat row halves: [h0 0..255 | h1 256..511] + pad
#define XSS 104   // 96 + 8 pad

#define W0_HALVES (48 * W0S)                 // 17280 (34560 B)
#define W1_HALVES (48 * W1S)                 // 24576 (49152 B)
#define IMG_HALVES (W0_HALVES + W1_HALVES)   // 41856

#define SMEM_BYTES 49152                     // max(W0 34560, W1 49152, structs 32576)

// shared aliasing offsets (bytes) — used after both hoists complete
#define HCAT_OFF 0
#define XS_OFF   16640
#define CT_OFF   23296
#define RED_OFF  31488

// d_ws layout (bytes)
#define WIMG_OFF 0
#define WIMG_BYTES (16 * IMG_HALVES * 2)     // 1,339,392
#define HX0_OFF WIMG_BYTES
#define HX_WORDS (2 * 16 * 16 * 256)
#define HX1_OFF (HX0_OFF + HX_WORDS * 4)
#define HX_TOTAL_BYTES (2 * HX_WORDS * 4)    // 1 MiB

typedef _Float16 f16x8 __attribute__((ext_vector_type(8)));
typedef float f32x4 __attribute__((ext_vector_type(4)));
typedef unsigned int u32x4 __attribute__((ext_vector_type(4)));

#define PINV(x) asm volatile("" : "+v"(x))

__device__ __forceinline__ void bar_lds() {
  asm volatile("s_waitcnt lgkmcnt(0)" ::: "memory");
  __builtin_amdgcn_s_barrier();
  __builtin_amdgcn_sched_barrier(0);
}

// MALL-routed coherent ops (sc0 sc1), placement-independent (R4..R11-proven)
__device__ __forceinline__ void st_u32_sys(unsigned* p, unsigned v) {
  asm volatile("global_store_dword %0, %1, off sc0 sc1" :: "v"(p), "v"(v) : "memory");
}
__device__ __forceinline__ void issue4_sys(const unsigned* p, u32x4& a, u32x4& b,
                                           u32x4& c, u32x4& d) {
  asm volatile(
      "global_load_dwordx4 %0, %4, off sc0 sc1\n\t"
      "global_load_dwordx4 %1, %4, off offset:16 sc0 sc1\n\t"
      "global_load_dwordx4 %2, %4, off offset:32 sc0 sc1\n\t"
      "global_load_dwordx4 %3, %4, off offset:48 sc0 sc1"
      : "=&v"(a), "=&v"(b), "=&v"(c), "=&v"(d) : "v"(p) : "memory");
}
__device__ __forceinline__ void ld4b_sys(const unsigned* p, u32x4& a, u32x4& b,
                                         u32x4& c, u32x4& d) {
  asm volatile(
      "global_load_dwordx4 %0, %4, off sc0 sc1\n\t"
      "global_load_dwordx4 %1, %4, off offset:16 sc0 sc1\n\t"
      "global_load_dwordx4 %2, %4, off offset:32 sc0 sc1\n\t"
      "global_load_dwordx4 %3, %4, off offset:48 sc0 sc1\n\t"
      "s_waitcnt vmcnt(0)"
      : "=&v"(a), "=&v"(b), "=&v"(c), "=&v"(d) : "v"(p) : "memory");
}

__device__ __forceinline__ bool tags_ok(const u32x4& a, const u32x4& b,
                                        const u32x4& c, const u32x4& e, unsigned tg) {
  u32x4 m4 = __builtin_elementwise_min(__builtin_elementwise_min(a, b),
                                       __builtin_elementwise_min(c, e));
  unsigned m = m4.x;
  m = m4.y < m ? m4.y : m;
  m = m4.z < m ? m4.z : m;
  m = m4.w < m ? m4.w : m;
  return (m >> 16) == tg;
}

__device__ __forceinline__ void unpack16(_Float16* d, const u32x4& a, const u32x4& b,
                                         const u32x4& c, const u32x4& e) {
  u32x4 w0 = { (a.x & 0xffffu) | (a.y << 16), (a.z & 0xffffu) | (a.w << 16),
               (b.x & 0xffffu) | (b.y << 16), (b.z & 0xffffu) | (b.w << 16) };
  u32x4 w1 = { (c.x & 0xffffu) | (c.y << 16), (c.z & 0xffffu) | (c.w << 16),
               (e.x & 0xffffu) | (e.y << 16), (e.z & 0xffffu) | (e.w << 16) };
  *(u32x4*)d = w0;
  *(u32x4*)(d + 8) = w1;
}

// Weight image per block j (halves): W0 [48][W0S] (x cols 0..74, h cols 96..351),
// W1 [48][512] (h0 cols 0..255, h1 cols 256..511); row = gate*16+u.
__global__ void prep_wimg(const float* __restrict__ wih0, const float* __restrict__ whh0,
                          const float* __restrict__ wih1, const float* __restrict__ whh1,
                          _Float16* __restrict__ wimg) {
  const int total = 16 * IMG_HALVES;
  for (int i = blockIdx.x * blockDim.x + threadIdx.x; i < total;
       i += gridDim.x * blockDim.x) {
    const int j = i / IMG_HALVES;
    int rem = i - j * IMG_HALVES;
    float val = 0.f;
    if (rem < W0_HALVES) {
      const int row = rem / W0S, k = rem - row * W0S;
      const int gate = row >> 4, u = row & 15;
      const int grow = gate * NH + j * 16 + u;
      if (k < NF) val = wih0[grow * NF + k];
      else if (k >= 96 && k < 352) val = whh0[grow * NH + (k - 96)];
    } else {
      rem -= W0_HALVES;
      const int row = rem >> 9, k = rem & 511;
      const int gate = row >> 4, u = row & 15;
      const int grow = gate * NH + j * 16 + u;
      if (k < 256) val = wih1[grow * NH + k];
      else         val = whh1[grow * NH + (k - 256)];
    }
    wimg[i] = (_Float16)val;
  }
}

__global__ __launch_bounds__(512, 1) void gru_mfma(
    const float* __restrict__ x,
    const float* __restrict__ b_ih0, const float* __restrict__ b_hh0,
    const float* __restrict__ b_ih1, const float* __restrict__ b_hh1,
    const float* __restrict__ w_lin, const float* __restrict__ b_lin,
    const _Float16* __restrict__ wimg,
    unsigned* __restrict__ hx0, unsigned* __restrict__ hx1,
    float* __restrict__ out)
{
  const int tid = threadIdx.x;
  const int bid = blockIdx.x;
  const int gr = (bid & 7) + ((bid >> 7) << 3);
  const int j  = (bid >> 3) & 15;

  __shared__ f16x8 smem8[SMEM_BYTES / 16];          // 49152 B
  _Float16* Wst  = (_Float16*)smem8;
  _Float16* hcat = (_Float16*)((char*)smem8 + HCAT_OFF);
  _Float16* xs   = (_Float16*)((char*)smem8 + XS_OFF);
  float (*ctile)[64][4] = (float(*)[64][4])((char*)smem8 + CT_OFF);
  float (*red)[17]      = (float(*)[17])((char*)smem8 + RED_OFF);

  int dead = 0, spins = 0;

  const int t8 = tid & 255;
  const int row = t8 >> 4, u = t8 & 15, gu = j * 16 + u;
  const int wid = tid >> 6, lane = tid & 63;
  const int lrow = lane & 15, lko = (lane >> 4) * 8;
  const int chunk = gr * 4096 + row * 256 + u * 16;

  float gbr, gbz, gbnx, gbnh;
  if (tid < 256) {
    gbr  = b_ih0[gu] + b_hh0[gu];
    gbz  = b_ih0[NH + gu] + b_hh0[NH + gu];
    gbnx = b_ih0[2 * NH + gu];
    gbnh = b_hh0[2 * NH + gu];
  } else {
    gbr  = b_ih1[gu] + b_hh1[gu];
    gbz  = b_ih1[NH + gu] + b_hh1[NH + gu];
    gbnx = b_ih1[2 * NH + gu];
    gbnh = b_hh1[2 * NH + gu];
  }

  f16x8 Bf[16];
  // ---- phase A: stage W0 image, hoist L0-wave fragments ----
  {
    const float4* src = (const float4*)(wimg + (size_t)j * IMG_HALVES);
    float4* dst = (float4*)Wst;
    for (int i = tid; i < W0_HALVES / 8; i += 512) dst[i] = src[i];
  }
  __syncthreads();   // Sa: W0 staged
  if (wid == 0) {            // ct0 = L0-r
    const _Float16* wb = Wst + lrow * W0S + lko;
    #pragma unroll
    for (int i = 0; i < 11; ++i) { Bf[i] = *(const f16x8*)(wb + i * 32); PINV(Bf[i]); }
  } else if (wid == 1) {     // ct1 = L0-z
    const _Float16* wb = Wst + (16 + lrow) * W0S + lko;
    #pragma unroll
    for (int i = 0; i < 11; ++i) { Bf[i] = *(const f16x8*)(wb + i * 32); PINV(Bf[i]); }
  } else if (wid == 2) {     // ct2 = L0-nx (x-part only)
    const _Float16* wb = Wst + (32 + lrow) * W0S + lko;
    #pragma unroll
    for (int i = 0; i < 3; ++i) { Bf[i] = *(const f16x8*)(wb + i * 32); PINV(Bf[i]); }
  } else if (wid == 3) {     // ct3 = L0-nh (h-part)
    const _Float16* wb = Wst + (32 + lrow) * W0S + lko;
    #pragma unroll
    for (int i = 0; i < 8; ++i) { Bf[i] = *(const f16x8*)(wb + (3 + i) * 32); PINV(Bf[i]); }
  }
  __syncthreads();   // Sb: W0 hoist done

  // ---- phase B: stage W1 image OVER the same buffer, hoist L1-wave frags ----
  {
    const float4* src = (const float4*)(wimg + (size_t)j * IMG_HALVES + W0_HALVES);
    float4* dst = (float4*)Wst;
    for (int i = tid; i < W1_HALVES / 8; i += 512) dst[i] = src[i];
  }
  __syncthreads();   // Sc: W1 staged
  if (wid == 4) {            // ct4 = L1-r (h0 cols 0..7, h1 cols 8..15)
    const _Float16* wn = Wst + lrow * W1S + lko;
    #pragma unroll
    for (int i = 0; i < 16; ++i) { Bf[i] = *(const f16x8*)(wn + i * 32); PINV(Bf[i]); }
  } else if (wid == 5) {     // ct5 = L1-z
    const _Float16* wn = Wst + (16 + lrow) * W1S + lko;
    #pragma unroll
    for (int i = 0; i < 16; ++i) { Bf[i] = *(const f16x8*)(wn + i * 32); PINV(Bf[i]); }
  } else if (wid == 6) {     // ct6 = L1-nx (h0 cols)
    const _Float16* wn = Wst + (32 + lrow) * W1S + lko;
    #pragma unroll
    for (int i = 0; i < 8; ++i) { Bf[i] = *(const f16x8*)(wn + i * 32); PINV(Bf[i]); }  
  } else if (wid == 7) {     // ct7 = L1-nh (h1 cols)
    const _Float16* wn = Wst + (32 + lrow) * W1S + lko;
    #pragma unroll
    for (int i = 0; i < 8; ++i) { Bf[i] = *(const f16x8*)(wn + (8 + i) * 32); PINV(Bf[i]); }
  }
  __syncthreads();   // Sd: W1 hoist done; buffer may be clobbered

  for (int i = tid; i < 16 * HCS; i += 512) hcat[i] = (_Float16)0.f;
  for (int i = tid; i < 2 * 16 * XSS; i += 512) xs[i] = (_Float16)0.f;

  int xr_[3], xc_[3]; bool xv_[3];
  #pragma unroll
  for (int i = 0; i < 3; ++i) {
    const int idx = i * 512 + tid;
    xv_[i] = idx < 16 * NF;
    xr_[i] = xv_[i] ? idx / NF : 0;
    xc_[i] = xv_[i] ? idx % NF : 0;
  }
  const float* __restrict__ xbase = x + (size_t)(gr * 16) * NS * NF;
  #pragma unroll
  for (int i = 0; i < 3; ++i)
    if (xv_[i]) xs[xr_[i] * XSS + xc_[i]] =
        (_Float16)xbase[(size_t)xr_[i] * NS * NF + xc_[i]];

  float h0f = 0.f, h1f = 0.f;
  __syncthreads();   // Se: loop structs ready

  for (int p = 0; p <= NS; ++p) {
    const int par = p & 1;

    // (1) x prefetch
    float xf[3];
    if (p + 1 < NS) {
      #pragma unroll
      for (int i = 0; i < 3; ++i)
        if (xv_[i]) xf[i] = xbase[((size_t)xr_[i] * NS + (p + 1)) * NF + xc_[i]];
    }

    // (a) half1: async h1[p-2] gather (published a full phase ago)
    u32x4 G0, G1, G2, G3;
    if (tid >= 256 && p >= 2)
      issue4_sys(hx1 + par * 65536 + chunk, G0, G1, G2, G3);

    // (2)+(3) per-wave A-fragments + pre-barrier MFMAs
    const _Float16* __restrict__ xp = xs + par * (16 * XSS) + lrow * XSS + lko;
    const _Float16* __restrict__ hp = hcat + lrow * HCS + lko;
    f32x4 acc45 = {0.f, 0.f, 0.f, 0.f};   // wid4/5 carried across S2
    if (wid <= 1) {
      f16x8 xa0 = *(const f16x8*)(xp);
      f16x8 xa1 = *(const f16x8*)(xp + 32);
      f16x8 xa2 = *(const f16x8*)(xp + 64);
      f16x8 hfr[8];
      #pragma unroll
      for (int kb = 0; kb < 8; ++kb) hfr[kb] = *(const f16x8*)(hp + kb * 32);
      f32x4 a = {0.f, 0.f, 0.f, 0.f};
      a = __builtin_amdgcn_mfma_f32_16x16x32_f16(xa0, Bf[0], a, 0, 0, 0);
      a = __builtin_amdgcn_mfma_f32_16x16x32_f16(xa1, Bf[1], a, 0, 0, 0);
      a = __builtin_amdgcn_mfma_f32_16x16x32_f16(xa2, Bf[2], a, 0, 0, 0);
      #pragma unroll
      for (int kb = 0; kb < 8; ++kb)
        a = __builtin_amdgcn_mfma_f32_16x16x32_f16(hfr[kb], Bf[3 + kb], a, 0, 0, 0);
      *(f32x4*)&ctile[wid][lane][0] = a;
    } else if (wid == 2) {
      f16x8 xa0 = *(const f16x8*)(xp);
      f16x8 xa1 = *(const f16x8*)(xp + 32);
      f16x8 xa2 = *(const f16x8*)(xp + 64);
      f32x4 a = {0.f, 0.f, 0.f, 0.f};
      a = __builtin_amdgcn_mfma_f32_16x16x32_f16(xa0, Bf[0], a, 0, 0, 0);
      a = __builtin_amdgcn_mfma_f32_16x16x32_f16(xa1, Bf[1], a, 0, 0, 0);
      a = __builtin_amdgcn_mfma_f32_16x16x32_f16(xa2, Bf[2], a, 0, 0, 0);
      *(f32x4*)&ctile[2][lane][0] = a;
    } else if (wid == 3) {
      f16x8 hfr[8];
      #pragma unroll
      for (int kb = 0; kb < 8; ++kb) hfr[kb] = *(const f16x8*)(hp + kb * 32);
      f32x4 a = {0.f, 0.f, 0.f, 0.f};
      #pragma unroll
      for (int kb = 0; kb < 8; ++kb)
        a = __builtin_amdgcn_mfma_f32_16x16x32_f16(hfr[kb], Bf[kb], a, 0, 0, 0);
      *(f32x4*)&ctile[3][lane][0] = a;
    } else if (wid == 4 || wid == 5) {
      f16x8 hfr[8];
      #pragma unroll
      for (int kb = 0; kb < 8; ++kb) hfr[kb] = *(const f16x8*)(hp + kb * 32);
      #pragma unroll
      for (int kb = 0; kb < 8; ++kb)
        acc45 = __builtin_amdgcn_mfma_f32_16x16x32_f16(hfr[kb], Bf[kb], acc45, 0, 0, 0);
    } else if (wid == 6) {
      f16x8 hfr[8];
      #pragma unroll
      for (int kb = 0; kb < 8; ++kb) hfr[kb] = *(const f16x8*)(hp + kb * 32);
      f32x4 a = {0.f, 0.f, 0.f, 0.f};
      #pragma unroll
      for (int kb = 0; kb < 8; ++kb)
        a = __builtin_amdgcn_mfma_f32_16x16x32_f16(hfr[kb], Bf[kb], a, 0, 0, 0);
      *(f32x4*)&ctile[6][lane][0] = a;
    }
    // wid7: no pre-barrier MFMA

    // (3.5) stage x[p+1]
    if (p + 1 < NS) {
      #pragma unroll
      for (int i = 0; i < 3; ++i)
        if (xv_[i]) xs[((p + 1) & 1) * (16 * XSS) + xr_[i] * XSS + xc_[i]] =
            (_Float16)xf[i];
    }
    bar_lds();   // S1: ct0..3,ct6 ready; hcat/xs(par) reads done

    // (4) CONCURRENT: half0 = L0 gates + publish h0[p]; half1 = validate h1[p-2]
    const int li = ((row >> 2) << 4) | u, rg = row & 3;
    if (tid < 256) {
      if (p < NS) {
        const float ar = ctile[0][li][rg] + gbr;
        const float az = ctile[1][li][rg] + gbz;
        const float nx = ctile[2][li][rg] + gbnx;
        const float nh = ctile[3][li][rg] + gbnh;
        const float r = 1.f / (1.f + __expf(-ar));
        const float z = 1.f / (1.f + __expf(-az));
        const float n = tanhf(nx + r * nh);
        h0f = (1.f - z) * n + z * h0f;
        union { _Float16 h; unsigned short s; } c; c.h = (_Float16)h0f;
        st_u32_sys(hx0 + par * 65536 + gr * 4096 + row * 256 + gu,
                   (unsigned)c.s | ((unsigned)(p + 1) << 16));
      }
    } else {
      if (p >= 2) {
        asm volatile("s_waitcnt vmcnt(0)"
                     : "+v"(G0), "+v"(G1), "+v"(G2), "+v"(G3) :: "memory");
        while (!tags_ok(G0, G1, G2, G3, (unsigned)(p - 1))) {
          if (++spins > 200000) { dead = 1; break; }
          __builtin_amdgcn_s_sleep(1);
          ld4b_sys(hx1 + par * 65536 + chunk, G0, G1, G2, G3);
        }
        unpack16(hcat + row * HCS + 256 + u * 16, G0, G1, G2, G3);
      }
    }
    bar_lds();   // S2: h1[p-2] in hcat; h0[p] published

    // (6) half0: async h0[p] gather; waves 4/5/7: h1-part MFMAs
    u32x4 A0, A1, A2, A3;
    if (tid < 256 && p < NS)
      issue4_sys(hx0 + par * 65536 + chunk, A0, A1, A2, A3);
    if (wid == 4 || wid == 5) {
      const _Float16* hq = hcat + lrow * HCS + 256 + lko;
      f16x8 h1r[8];
      #pragma unroll
      for (int kb = 0; kb < 8; ++kb) h1r[kb] = *(const f16x8*)(hq + kb * 32);
      #pragma unroll
      for (int kb = 0; kb < 8; ++kb)
        acc45 = __builtin_amdgcn_mfma_f32_16x16x32_f16(h1r[kb], Bf[8 + kb], acc45, 0, 0, 0);
      *(f32x4*)&ctile[wid][lane][0] = acc45;
    } else if (wid == 7) {
      const _Float16* hq = hcat + lrow * HCS + 256 + lko;
      f16x8 h1r[8];
      #pragma unroll
      for (int kb = 0; kb < 8; ++kb) h1r[kb] = *(const f16x8*)(hq + kb * 32);
      f32x4 a = {0.f, 0.f, 0.f, 0.f};
      #pragma unroll
      for (int kb = 0; kb < 8; ++kb)
        a = __builtin_amdgcn_mfma_f32_16x16x32_f16(h1r[kb], Bf[kb], a, 0, 0, 0);
      *(f32x4*)&ctile[7][lane][0] = a;
    }
    bar_lds();   // S3: ct4..7 ready

    // (7)/(8) CONCURRENT: half1 = L1 gates + publish h1[p-1]; half0 = validate h0[p]
    if (tid >= 256) {
      if (p >= 1) {
        const float ar = ctile[4][li][rg] + gbr;
        const float az = ctile[5][li][rg] + gbz;
        const float nx = ctile[6][li][rg] + gbnx;
        const float nh = ctile[7][li][rg] + gbnh;
        const float r = 1.f / (1.f + __expf(-ar));
        const float z = 1.f / (1.f + __expf(-az));
        const float n = tanhf(nx + r * nh);
        h1f = (1.f - z) * n + z * h1f;
        union { _Float16 h; unsigned short s; } c; c.h = (_Float16)h1f;
        st_u32_sys(hx1 + ((p - 1) & 1) * 65536 + gr * 4096 + row * 256 + gu,
                   (unsigned)c.s | ((unsigned)p << 16));
      }
    } else {
      if (p < NS) {
        asm volatile("s_waitcnt vmcnt(0)"
                     : "+v"(A0), "+v"(A1), "+v"(A2), "+v"(A3) :: "memory");
        while (!tags_ok(A0, A1, A2, A3, (unsigned)(p + 1))) {
          if (++spins > 200000) { dead = 1; break; }
          __builtin_amdgcn_s_sleep(1);
          ld4b_sys(hx0 + par * 65536 + chunk, A0, A1, A2, A3);
        }
        unpack16(hcat + row * HCS + u * 16, A0, A1, A2, A3);
      }
    }
    bar_lds();   // S4
  }

  // ---- tail: half1 gathers h1[NS-1] (slot (NS-1)&1, tag NS) ----
  if (tid >= 256) {
    u32x4 C0, C1, C2, C3;
    const unsigned* src = hx1 + ((NS - 1) & 1) * 65536 + chunk;
    for (;;) {
      ld4b_sys(src, C0, C1, C2, C3);
      if (tags_ok(C0, C1, C2, C3, (unsigned)NS)) break;
      if (++spins > 200000) { dead = 1; break; }
      __builtin_amdgcn_s_sleep(1);
    }
    unpack16(hcat + row * HCS + 256 + u * 16, C0, C1, C2, C3);
  }
  __syncthreads();
  if (tid < 256) {
    float part = 0.f;
    #pragma unroll
    for (int e = 0; e < 16; ++e)
      part += (float)hcat[row * HCS + 256 + u * 16 + e] * w_lin[u * 16 + e];
    red[row][u] = part;
  }
  __syncthreads();
  if (j == 0 && tid < 16) {
    float s = 0.f;
    #pragma unroll
    for (int e = 0; e < 16; ++e) s += red[tid][e];
    out[gr * 16 + tid] = s + b_lin[0];
  }
}

extern "C" void kernel_launch(void* const* d_in, const int* in_sizes, int n_in,
                              void* d_out, int out_size, void* d_ws, size_t ws_size,
                              hipStream_t stream) {
  (void)in_sizes; (void)n_in; (void)out_size; (void)ws_size;
  const float* x     = (const float*)d_in[0];
  const float* w_ih0 = (const float*)d_in[1];
  const float* w_hh0 = (const float*)d_in[2];
  const float* b_ih0 = (const float*)d_in[3];
  const float* b_hh0 = (const float*)d_in[4];
  const float* w_ih1 = (const float*)d_in[5];
  const float* w_hh1 = (const float*)d_in[6];
  const float* b_ih1 = (const float*)d_in[7];
  const float* b_hh1 = (const float*)d_in[8];
  const float* w_lin = (const float*)d_in[9];
  const float* b_lin = (const float*)d_in[10];

  char* ws = (char*)d_ws;
  _Float16* wimg = (_Float16*)(ws + WIMG_OFF);
  unsigned* hx0  = (unsigned*)(ws + HX0_OFF);
  unsigned* hx1  = (unsigned*)(ws + HX1_OFF);

  hipMemsetAsync(ws + HX0_OFF, 0, HX_TOTAL_BYTES, stream);
  prep_wimg<<<1024, 256, 0, stream>>>(w_ih0, w_hh0, w_ih1, w_hh1, wimg);
  gru_mfma<<<256, 512, 0, stream>>>(x, b_ih0, b_hh0, b_ih1, b_hh1,
                                    w_lin, b_lin, wimg, hx0, hx1,
                                    (float*)d_out);
}